// Round 15
// baseline (1618.193 us; speedup 1.0000x reference)
//
#include <hip/hip_runtime.h>
#include <hip/hip_bf16.h>
#include <math.h>

// ---------------------------------------------------------------------------
// N=1, C=128, H=64, W=128, W1=64, HN=64, 2HN=128, NH=8, hd=16, L=6.
// GEMM 64x64 tiles; attention on MFMA (block = b/strip/half, wave = head).
// y-out-proj + x-qkv folded into one GEMM via precomputed W2 = iw_x @ ow_y.
// ---------------------------------------------------------------------------

typedef __attribute__((ext_vector_type(8))) short bf16x8;
typedef __attribute__((ext_vector_type(4))) float f32x4;
typedef __hip_bfloat16 bf16;

__device__ __forceinline__ float b2f(unsigned short u) {
  return __uint_as_float((unsigned)u << 16);
}
__device__ __forceinline__ short f2bs(float x) {
  bf16 h = __float2bfloat16(x);
  short s;
  __builtin_memcpy(&s, &h, 2);
  return s;
}
__device__ __forceinline__ int ymap(int t, int D0, int D1) {
  return (t % D0) * (2 * D1) + ((t / D0) & 1) * D1 + t / (2 * D0);
}

// ============================= small setup kernels ==========================

__global__ void k_build_feat(const float* __restrict__ L, const float* __restrict__ R,
                             float* __restrict__ feat, int W) {
  int t = blockIdx.x;
  int c = threadIdx.x;
  int b = t & 127;
  int w = t >> 7;
  const float* src = (b < 64) ? L : R;
  int h = b & 63;
  feat[(size_t)t * 128 + c] = src[((size_t)c * 64 + h) * W + w];
}

struct FDesc { const float* s; bf16* d; int n; };
struct FArgs { FDesc d[9]; int cum[10]; int nprob; };
__global__ void k_f2b_multi(FArgs fa) {
  int bid = blockIdx.x;
  int p = 0;
  while (p + 1 < fa.nprob && bid >= fa.cum[p + 1]) ++p;
  const FDesc d = fa.d[p];
  int i = (bid - fa.cum[p]) * 1024 + threadIdx.x * 4;
  if (i + 3 < d.n) {
    float4 x = *(const float4*)(d.s + i);
    d.d[i + 0] = __float2bfloat16(x.x);
    d.d[i + 1] = __float2bfloat16(x.y);
    d.d[i + 2] = __float2bfloat16(x.z);
    d.d[i + 3] = __float2bfloat16(x.w);
  } else {
    for (int z = 0; z < 4 && i + z < d.n; ++z) d.d[i + z] = __float2bfloat16(d.s[i + z]);
  }
}

__global__ void k_wfullb(const float* __restrict__ w2, bf16* __restrict__ wf) {
  int bid = blockIdx.x;
  int l = bid >> 7, co = bid & 127;
  int ci = threadIdx.x;
  const float* src = w2 + (size_t)l * 128 * 128 * 9;
  bf16* dst = wf + (size_t)l * 128 * 1152;
#pragma unroll
  for (int ky = 0; ky < 3; ky++)
#pragma unroll
    for (int kx = 0; kx < 3; kx++)
      dst[(size_t)co * 1152 + (kx * 3 + ky) * 128 + ci] =
          __float2bfloat16(src[((size_t)(co * 128 + ci) * 3 + ky) * 3 + kx]);
}

// zero guard rows of the pos tables
__global__ void k_zero_guard(bf16* p0, bf16* p1) {
  int t = threadIdx.x;
  p0[255 * 256 + t] = __float2bfloat16(0.0f);
  p1[127 * 256 + t] = __float2bfloat16(0.0f);
}

// combined weights W2[p][j][c] = sum_t iw[p][j][t] * ow[p][t][c]
// grid = 12 probs * 6 row-chunks(64); 256 thr: 4 thr/row, 32 cols each
struct WCArgs { const bf16* iw[12]; const bf16* ow[12]; bf16* out[12]; };
__global__ __launch_bounds__(256) void k_wcomb(WCArgs a) {
  __shared__ bf16 sOw[128 * 128];
  int p = blockIdx.x / 6, rc = blockIdx.x % 6;
  const bf16* iw = a.iw[p];
  const bf16* ow = a.ow[p];
  for (int i = threadIdx.x; i < 128 * 16; i += 256)
    ((bf16x8*)sOw)[i] = ((const bf16x8*)ow)[i];
  __syncthreads();
  int row = rc * 64 + (threadIdx.x >> 2);
  int seg = (threadIdx.x & 3) * 32;
  float acc[32];
#pragma unroll
  for (int c = 0; c < 32; ++c) acc[c] = 0.f;
  for (int t = 0; t < 128; ++t) {
    float av = b2f((unsigned short)iw[row * 128 + t]);
#pragma unroll
    for (int c = 0; c < 32; ++c)
      acc[c] = fmaf(av, b2f((unsigned short)sOw[t * 128 + seg + c]), acc[c]);
  }
  bf16* o = a.out[p] + (size_t)row * 128 + seg;
  for (int c = 0; c < 32; ++c) o[c] = __float2bfloat16(acc[c]);
}

// combined bias b2[p][j] = sum_t iw_f32[p][j][t]*ob[p][t] + ib[p][j]
struct BCArgs { const float* iwf[12]; const float* obf[12]; const float* ibf[12]; float* out[12]; };
__global__ void k_bcomb(BCArgs a) {
  int p = blockIdx.x, j = threadIdx.x;   // 384 threads
  const float* iw = a.iwf[p] + (size_t)j * 128;
  const float* ob = a.obf[p];
  float acc = a.ibf[p][j];
  for (int t = 0; t < 128; ++t) acc = fmaf(iw[t], ob[t], acc);
  a.out[p][j] = acc;
}

// raw combine: out[b][w][v] = (v>w) ? 0 : A+B+C+D  (bf16; ref has -inf there)
__global__ void k_rawcomb4(const float* __restrict__ A, const float* __restrict__ B2,
                           const float* __restrict__ C3, const float* __restrict__ D4,
                           bf16* __restrict__ out) {
  int i = blockIdx.x * 256 + threadIdx.x;
  int v = i & 127, w = (i >> 7) & 127;
  float rv = (v > w) ? 0.0f : (A[i] + B2[i] + C3[i] + D4[i]);
  out[i] = __float2bfloat16(rv);
}

// ============================= LN multi =====================================

struct LDesc { const float* src; bf16* dst; const float* g; const float* be;
               int ntok, Bout, PBin, offIn; };
struct LArgs { LDesc d[4]; int cum[5]; int nprob; };

__global__ __launch_bounds__(256) void k_ln_multi(LArgs la) {
  int bid = blockIdx.x;
  int p = 0;
  while (p + 1 < la.nprob && bid >= la.cum[p + 1]) ++p;
  const LDesc d = la.d[p];
  int t = (bid - la.cum[p]) * 4 + (threadIdx.x >> 6);
  int lane = threadIdx.x & 63;
  if (t >= d.ntok) return;
  int w = t / d.Bout, b = t - w * d.Bout;
  const float* row = d.src + (size_t)(w * d.PBin + d.offIn + b) * 128;
  float x0 = row[lane], x1 = row[lane + 64];
  float s = x0 + x1;
#pragma unroll
  for (int o = 32; o; o >>= 1) s += __shfl_xor(s, o, 64);
  float m = s * (1.0f / 128.0f);
  float d0 = x0 - m, d1 = x1 - m;
  float v = d0 * d0 + d1 * d1;
#pragma unroll
  for (int o = 32; o; o >>= 1) v += __shfl_xor(v, o, 64);
  float r = 1.0f / sqrtf(v * (1.0f / 128.0f) + 1e-5f);
  bf16* orow = d.dst + (size_t)t * 128;
  orow[lane]      = __float2bfloat16(d0 * r * d.g[lane]      + d.be[lane]);
  orow[lane + 64] = __float2bfloat16(d1 * r * d.g[lane + 64] + d.be[lane + 64]);
}

// ============================= GEMM multi (64x64 tiles) =====================

struct GDesc {
  const bf16* A; const float* Af0; const float* Af1;
  const bf16* W; const float* bias;
  bf16* Cb; float* Cf; const float* resid;
  int M, N, K, lda, scaleN;
  int imode, iD0, iD1;
  int omode, oD0, oD1, ooff;
};
struct GArgs { GDesc d[6]; int cum[7]; int nprob; };

__global__ __launch_bounds__(256) void k_gemm_multi(GArgs ga) {
  __shared__ bf16x8 sA[64 * 4];
  __shared__ bf16x8 sB[64 * 4];
  int bid = blockIdx.x;
  int p = 0;
  while (p + 1 < ga.nprob && bid >= ga.cum[p + 1]) ++p;
  const GDesc d = ga.d[p];
  int local = bid - ga.cum[p];
  int tilesx = d.N >> 6;
  int ty = local / tilesx, tx = local - ty * tilesx;
  const int m0 = ty << 6, n0 = tx << 6;
  const int tid = threadIdx.x;
  const int lane = tid & 63;
  const int wave = tid >> 6;
  const int wm = wave >> 1, wn = wave & 1;
  const int fr = lane & 15;
  const int kc = lane >> 4;
  f32x4 acc[2][2];
#pragma unroll
  for (int f = 0; f < 2; f++)
#pragma unroll
    for (int g = 0; g < 2; g++) acc[f][g] = (f32x4){0.f, 0.f, 0.f, 0.f};

  for (int k0 = 0; k0 < d.K; k0 += 32) {
    {
      int row = tid >> 2, ch = tid & 3;
      int m = m0 + row;
      bf16x8 val = (bf16x8){0, 0, 0, 0, 0, 0, 0, 0};
      if (d.imode == 0) {
        if (m < d.M) val = *(const bf16x8*)(d.A + (size_t)m * d.lda + k0 + ch * 8);
      } else if (d.imode == 1) {
        if (m < d.M) {
          int ar = ymap(m, d.iD0, d.iD1);
          val = *(const bf16x8*)(d.A + (size_t)ar * d.lda + k0 + ch * 8);
        }
      } else if (d.imode == 2) {
        int kblk = k0 >> 7;
        int kx = kblk / 3, ky = kblk - kx * 3;
        int arow = m + (kx - 1) * 128;
        int y = (m & 127) + (ky - 1);
        if (arow >= 0 && arow < d.M && y >= 0 && y < 128)
          val = *(const bf16x8*)(d.A + (size_t)arow * d.lda + (k0 & 127) + ch * 8);
      } else {
        int kk = k0 + ch * 8;
        int w = m >> 7, y = m & 127;
        if (kk < 128) {
          float xo = fminf(fmaxf(w * 0.5f - 0.25f, 0.0f), 63.0f);
          int lo = (int)xo;
          int hi = (lo + 1 < 63) ? lo + 1 : 63;
          float f = xo - (float)lo;
          const float* a0 = d.Af0 + ((size_t)lo * 128 + y) * 128 + kk;
          const float* a1 = d.Af0 + ((size_t)hi * 128 + y) * 128 + kk;
#pragma unroll
          for (int z = 0; z < 8; ++z) val[z] = f2bs(a0[z] * (1.0f - f) + a1[z] * f);
        } else {
          const float* a0 = d.Af1 + (size_t)m * 128 + (kk - 128);
#pragma unroll
          for (int z = 0; z < 8; ++z) val[z] = f2bs(a0[z]);
        }
      }
      sA[row * 4 + (ch ^ ((row >> 2) & 3))] = val;
      bf16x8 bval = *(const bf16x8*)(d.W + (size_t)(n0 + row) * d.K + k0 + ch * 8);
      sB[row * 4 + (ch ^ ((row >> 2) & 3))] = bval;
    }
    __syncthreads();
    bf16x8 af[2], bg[2];
#pragma unroll
    for (int f = 0; f < 2; ++f) {
      int row = wm * 32 + f * 16 + fr;
      af[f] = sA[row * 4 + (kc ^ ((row >> 2) & 3))];
    }
#pragma unroll
    for (int g = 0; g < 2; ++g) {
      int row = wn * 32 + g * 16 + fr;
      bg[g] = sB[row * 4 + (kc ^ ((row >> 2) & 3))];
    }
#pragma unroll
    for (int f = 0; f < 2; ++f)
#pragma unroll
      for (int g = 0; g < 2; ++g)
        acc[f][g] = __builtin_amdgcn_mfma_f32_16x16x32_bf16(af[f], bg[g], acc[f][g], 0, 0, 0);
    __syncthreads();
  }
  const int r4 = (lane >> 4) << 2;
  const int ocol = lane & 15;
#pragma unroll
  for (int f = 0; f < 2; ++f) {
#pragma unroll
    for (int g = 0; g < 2; ++g) {
      int n = n0 + wn * 32 + g * 16 + ocol;
      float bv = d.bias ? d.bias[n] : 0.0f;
      bool sc = (n < d.scaleN);
#pragma unroll
      for (int i = 0; i < 4; ++i) {
        int m = m0 + wm * 32 + f * 16 + r4 + i;
        if (m < d.M) {
          int row;
          if (d.omode == 0) row = (m / d.oD0) * d.oD1 + d.ooff + (m % d.oD0);
          else row = ymap(m, d.oD0, d.oD1);
          size_t idx = (size_t)row * d.N + n;
          float val = acc[f][g][i] + bv;
          if (sc) val *= 0.25f;
          if (d.resid) val += d.resid[idx];
          if (d.Cb) d.Cb[idx] = __float2bfloat16(val);
          else d.Cf[idx] = val;
        }
      }
    }
  }
}

// ============================= attention (MFMA) =============================

struct ADesc {
  const bf16* Q; const bf16* K; const bf16* V;
  const bf16* PPb; bf16* O;
  float* raw0; float* raw1; float* raw2; float* raw3;
  int ldQ, ldK, ldV, Wlen, B, sflip, useMask;
};
struct AArgs { ADesc d[2]; int cum[3]; int nprob; };

template<int WLEN, int SGN>
__device__ __forceinline__ void attn_core(const ADesc& d, int b, int st, int h,
                                          int tid, bf16* Vt, bf16* Pl, bf16* T2l,
                                          bf16* Ost) {
  constexpr int NT = WLEN / 16;
  constexpr int R = WLEN - 1;
  const f32x4 z4 = (f32x4){0.f, 0.f, 0.f, 0.f};
  const bf16x8 zb = (bf16x8){0, 0, 0, 0, 0, 0, 0, 0};

  // ---- stage V^T (64 channel-rows of this half) [c][v], stride 136 ----
  {
    int q = tid & (WLEN / 2 - 1);
    int cc = tid >> ((WLEN == 128) ? 6 : 5);
    constexpr int CH = (WLEN == 128) ? 16 : 8;
    int cb = cc * CH;
    const bf16* v0p = d.V + ((size_t)(2 * q) * d.B + b) * d.ldV + h * 64 + cb;
    const bf16* v1p = d.V + ((size_t)(2 * q + 1) * d.B + b) * d.ldV + h * 64 + cb;
#pragma unroll
    for (int j = 0; j < CH; j += 8) {
      bf16x8 a = *(const bf16x8*)(v0p + j);
      bf16x8 bb = *(const bf16x8*)(v1p + j);
#pragma unroll
      for (int z = 0; z < 8; ++z) {
        unsigned pk = (unsigned)(unsigned short)a[z] |
                      ((unsigned)(unsigned short)bb[z] << 16);
        *(unsigned*)(Vt + (size_t)(cb + j + z) * 136 + 2 * q) = pk;
      }
    }
  }
  __syncthreads();

  const int wave = tid >> 6, l = tid & 63;
  const int lm = l & 15, lg = l >> 4;
  const bool zlane = (lg >= 2);
  bf16* Pw  = Pl + wave * (16 * 136);
  bf16* T2w = T2l + wave * (16 * 20);
  int p0[4], src[4], hi[4], tsel[4];
  bool csel[4];
#pragma unroll
  for (int i = 0; i < 4; ++i) {
    p0[i] = SGN * (lm - 4 * lg - i) + 15;
    src[i] = (l & 48) | (p0[i] & 15);
    hi[i] = p0[i] & 16;
    if (SGN == 1) {
      int t0 = lm + 15 - 4 * lg - i;
      csel[i] = (t0 < 16);
      tsel[i] = csel[i] ? t0 : t0 - 16;
    } else {
      int t0 = lm - 15 + 4 * lg + i;
      csel[i] = (t0 >= 0);
      tsel[i] = csel[i] ? t0 : t0 + 16;
    }
  }

  const int w0 = st * 16;
  const int chb = h * 64 + wave * 16 + lg * 8;

  bf16x8 qf = zb;
  if (!zlane) qf = *(const bf16x8*)(d.Q + ((size_t)(w0 + lm) * d.B + b) * d.ldQ + chb);

  const int U0 = (SGN == 1) ? (R - w0 - 15) : (R + w0 - WLEN + 1);
  const int Ub0 = (SGN == 1) ? (R - w0 - 15) : (R - (WLEN - 16) + w0 - 15);
  const bf16* t1p = d.PPb + (size_t)(U0 + lm) * 256 + 128 + chb;
  const bf16* t2p = d.PPb + (size_t)(Ub0 + lm) * 256 + chb;
  const int v0i = ((SGN == 1) ? 0 : (WLEN - 16)) + lm;
  const bf16* kp = d.K + ((size_t)v0i * d.B + b) * d.ldK + chb;
  const ptrdiff_t kstep = (ptrdiff_t)SGN * 16 * d.B * d.ldK;

  f32x4 t1a;
  {
    bf16x8 z = zb;
    if (!zlane) z = *(const bf16x8*)t1p;
    t1p += 16 * 256;
    t1a = __builtin_amdgcn_mfma_f32_16x16x32_bf16(qf, z, z4, 0, 0, 0);
  }
  int v = v0i;
#pragma unroll
  for (int j = 0; j < NT; ++j) {
    f32x4 t1b;
    {
      bf16x8 z = zb;
      if (!zlane) z = *(const bf16x8*)t1p;
      t1p += 16 * 256;
      t1b = __builtin_amdgcn_mfma_f32_16x16x32_bf16(qf, z, z4, 0, 0, 0);
    }
    bf16x8 kf = zb;
    if (!zlane) kf = *(const bf16x8*)kp;
    kp += kstep;
    f32x4 s4 = __builtin_amdgcn_mfma_f32_16x16x32_bf16(qf, kf, z4, 0, 0, 0);
    bf16x8 zA = zb, zB = zb;
    if (!zlane) {
      zA = *(const bf16x8*)t2p;
      zB = *(const bf16x8*)(t2p + 16 * 256);
    }
    t2p += 16 * 256;
    f32x4 t2A = __builtin_amdgcn_mfma_f32_16x16x32_bf16(zA, kf, z4, 0, 0, 0);
    f32x4 t2B = __builtin_amdgcn_mfma_f32_16x16x32_bf16(zB, kf, z4, 0, 0, 0);
#pragma unroll
    for (int i = 0; i < 4; ++i)
      T2w[lm * 20 + tsel[i]] = f2bs(csel[i] ? t2A[i] : t2B[i]);
    ushort4 t2u = *(const ushort4*)(T2w + lm * 20 + 4 * lg);
    unsigned short t2a[4] = {t2u.x, t2u.y, t2u.z, t2u.w};
#pragma unroll
    for (int i = 0; i < 4; ++i) {
      float va = __shfl(t1a[i], src[i], 64);
      float vb = __shfl(t1b[i], src[i], 64);
      float s = s4[i] + (hi[i] ? vb : va) + b2f(t2a[i]);
      Pw[(4 * lg + i) * 136 + v] = f2bs(__expf(s));
    }
    t1a = t1b;
    v += SGN * 16;
  }
  const bf16x8 ones = (bf16x8){0x3F80, 0x3F80, 0x3F80, 0x3F80,
                               0x3F80, 0x3F80, 0x3F80, 0x3F80};
  f32x4 oa = z4, rsm = z4;
#pragma unroll
  for (int vc = 0; vc < NT / 2; ++vc) {
    bf16x8 pf = *(const bf16x8*)(Pw + lm * 136 + vc * 32 + lg * 8);
    bf16x8 vf = *(const bf16x8*)(Vt + (size_t)(wave * 16 + lm) * 136 + vc * 32 + lg * 8);
    oa = __builtin_amdgcn_mfma_f32_16x16x32_bf16(pf, vf, oa, 0, 0, 0);
    rsm = __builtin_amdgcn_mfma_f32_16x16x32_bf16(pf, ones, rsm, 0, 0, 0);
  }
#pragma unroll
  for (int i = 0; i < 4; ++i)
    Ost[(4 * lg + i) * 80 + wave * 16 + lm] = f2bs(oa[i] / rsm[i]);
  __syncthreads();
  if (tid < 128) {
    int row = tid >> 3, ch8 = (tid & 7) * 8;
    bf16x8 vv = *(const bf16x8*)(Ost + row * 80 + ch8);
    *(bf16x8*)(d.O + ((size_t)(w0 + row) * d.B + b) * 128 + h * 64 + ch8) = vv;
  }
}

__global__ __launch_bounds__(256, 4) void k_attn_mfma(AArgs aa) {
  __shared__ bf16 Vt[64 * 136];
  __shared__ bf16 Pl[4 * 16 * 136];
  __shared__ bf16 T2l[4 * 16 * 20];
  __shared__ bf16 Ost[16 * 80];
  int bid = blockIdx.x;
  int p = 0;
  while (p + 1 < aa.nprob && bid >= aa.cum[p + 1]) ++p;
  const ADesc d = aa.d[p];
  int local = bid - aa.cum[p];
  int b = local % d.B;
  int rest = local / d.B;
  int ns = d.Wlen >> 4;
  int st = rest % ns, h = rest / ns;
  int tid = threadIdx.x;
  if (d.Wlen == 128) {
    if (d.sflip == 1) attn_core<128, 1>(d, b, st, h, tid, Vt, Pl, T2l, Ost);
    else attn_core<128, -1>(d, b, st, h, tid, Vt, Pl, T2l, Ost);
  } else {
    if (d.sflip == 1) attn_core<64, 1>(d, b, st, h, tid, Vt, Pl, T2l, Ost);
    else attn_core<64, -1>(d, b, st, h, tid, Vt, Pl, T2l, Ost);
  }
}

// Raw-score kernel (last layer): WLEN=128, SGN=1, causal mask, no O/softmax.
__global__ __launch_bounds__(256, 2) void k_attn_raw(ADesc d) {
  __shared__ bf16 T2l[4 * 16 * 20];
  constexpr int NT = 8;
  constexpr int R = 127;
  const f32x4 z4 = (f32x4){0.f, 0.f, 0.f, 0.f};
  const bf16x8 zb = (bf16x8){0, 0, 0, 0, 0, 0, 0, 0};
  int bid = blockIdx.x;
  int b = bid % d.B, st = bid / d.B;
  int tid = threadIdx.x;
  const int wave = tid >> 6, l = tid & 63;
  const int lm = l & 15, lg = l >> 4;
  const bool zlane = (lg >= 2);
  bf16* T2w = T2l + wave * (16 * 20);
  int p0[4];
#pragma unroll
  for (int i = 0; i < 4; ++i) p0[i] = (lm - 4 * lg - i) + 15;
  const int w0 = st * 16;
  f32x4 raw[NT];
#pragma unroll
  for (int vt = 0; vt < NT; ++vt) raw[vt] = z4;

  for (int hh = 0; hh < 2; ++hh) {
    const int e = wave * 2 + hh;
    const int chb = e * 16 + lg * 8;
    bf16x8 qf = zb;
    if (!zlane) qf = *(const bf16x8*)(d.Q + ((size_t)(w0 + lm) * d.B + b) * d.ldQ + chb);
    const int U0 = R - w0 - 15;
    f32x4 t1a;
    {
      int u = min(max(U0 + lm, 0), 2 * R);
      bf16x8 z = zb;
      if (!zlane) z = *(const bf16x8*)(d.PPb + (size_t)u * 256 + 128 + chb);
      t1a = __builtin_amdgcn_mfma_f32_16x16x32_bf16(qf, z, z4, 0, 0, 0);
    }
#pragma unroll
    for (int j = 0; j < NT; ++j) {
      const int vt = j;
      const int v = vt * 16 + lm;
      f32x4 t1b;
      {
        int u = min(max(U0 + (j + 1) * 16 + lm, 0), 2 * R);
        bf16x8 z = zb;
        if (!zlane) z = *(const bf16x8*)(d.PPb + (size_t)u * 256 + 128 + chb);
        t1b = __builtin_amdgcn_mfma_f32_16x16x32_bf16(qf, z, z4, 0, 0, 0);
      }
      bf16x8 kf = zb;
      if (!zlane) kf = *(const bf16x8*)(d.K + ((size_t)v * d.B + b) * d.ldK + chb);
      f32x4 s4 = __builtin_amdgcn_mfma_f32_16x16x32_bf16(qf, kf, z4, 0, 0, 0);
      const int Ub = R + vt * 16 - w0 - 15;
#pragma unroll
      for (int u2 = 0; u2 < 2; ++u2) {
        int ua = min(max(Ub + u2 * 16 + lm, 0), 2 * R);
        bf16x8 z = zb;
        if (!zlane) z = *(const bf16x8*)(d.PPb + (size_t)ua * 256 + chb);
        f32x4 t2 = __builtin_amdgcn_mfma_f32_16x16x32_bf16(z, kf, z4, 0, 0, 0);
#pragma unroll
        for (int i = 0; i < 4; ++i) {
          int u = Ub + u2 * 16 + 4 * lg + i;
          int t = R + v - u - w0;
          if (t >= 0 && t < 16) T2w[lm * 20 + t] = f2bs(t2[i]);
        }
      }
      ushort4 t2u = *(const ushort4*)(T2w + lm * 20 + 4 * lg);
      unsigned short t2a[4] = {t2u.x, t2u.y, t2u.z, t2u.w};
#pragma unroll
      for (int i = 0; i < 4; ++i) {
        int src = (l & 48) | (p0[i] & 15);
        float va = __shfl(t1a[i], src, 64);
        float vb = __shfl(t1b[i], src, 64);
        float s = s4[i] + ((p0[i] & 16) ? vb : va) + b2f(t2a[i]);
        if (v > (w0 + 4 * lg + i)) s = -INFINITY;
        raw[vt][i] += s;
      }
      t1a = t1b;
    }
  }
  float* rp = (wave == 0) ? d.raw0 : (wave == 1) ? d.raw1 : (wave == 2) ? d.raw2 : d.raw3;
#pragma unroll
  for (int vt = 0; vt < NT; ++vt)
#pragma unroll
    for (int i = 0; i < 4; ++i)
      rp[((size_t)b * 128 + (w0 + 4 * lg + i)) * 128 + vt * 16 + lm] = raw[vt][i];
}

// ============================= host =========================================

extern "C" void kernel_launch(void* const* d_in, const int* in_sizes, int n_in,
                              void* d_out, int out_size, void* d_ws, size_t ws_size,
                              hipStream_t stream) {
  (void)in_sizes; (void)n_in; (void)out_size; (void)ws_size;
  const float* FLt  = (const float*)d_in[0];
  const float* FRt  = (const float*)d_in[1];
  const float* FL1t = (const float*)d_in[2];
  const float* FR1t = (const float*)d_in[3];
  const float* PE   = (const float*)d_in[4];
  const float* PE1  = (const float*)d_in[5];
  const float* PEY  = (const float*)d_in[6];
  const float* PEY1 = (const float*)d_in[7];
  const float* SA_IW = (const float*)d_in[8];
  const float* SA_IB = (const float*)d_in[9];
  const float* SA_OW = (const float*)d_in[10];
  const float* SA_OB = (const float*)d_in[11];
  const float* SA_N1G = (const float*)d_in[12];
  const float* SA_N1B = (const float*)d_in[13];
  const float* SA_N2G = (const float*)d_in[14];
  const float* SA_N2B = (const float*)d_in[15];
  const float* CA_IW = (const float*)d_in[16];
  const float* CA_IB = (const float*)d_in[17];
  const float* CA_OW = (const float*)d_in[18];
  const float* CA_OB = (const float*)d_in[19];
  const float* CA_N1G = (const float*)d_in[20];
  const float* CA_N1B = (const float*)d_in[21];
  const float* CA_N2G = (const float*)d_in[22];
  const float* CA_N2B = (const float*)d_in[23];
  const float* MW1 = (const float*)d_in[24];
  const float* MB1 = (const float*)d_in[25];
  const float* MW2 = (const float*)d_in[26];
  const float* MB2 = (const float*)d_in[27];

  float* ws = (float*)d_ws;
  float* FEAT  = ws;                       // [16384,128]
  float* FEAT1 = ws + 2097152;             // [8192,128]   (raw0 at last layer)
  float* FN2   = ws + 3145728;             // [8192,128]   (raw1 at last layer)
  bf16* PP0b   = (bf16*)(ws + 4194304);    // [256,256] bf16 (row 255 = guard)
  bf16* PP1b   = (bf16*)(ws + 4259840);    // [128,256] bf16 (row 127 = guard)
  float* B2f   = ws + 4276224;             // [12][384] fp32 combined bias
  bf16* hb = (bf16*)(ws + 4292608);
  bf16* QKV   = hb;                        // 6,291,456
  bf16* QKV1  = hb + 6291456;              // 3,145,728
  bf16* Xb    = hb + 9437184;              // 2,097,152
  bf16* XBb   = hb + 11534336;             // 1,048,576
  bf16* Ob    = hb + 12582912;             // 2,097,152  (raw2 at last layer)
  bf16* Ob1   = hb + 14680064;             // 1,048,576
  bf16* PEb   = hb + 15728640;             // 32,768
  bf16* PE1b  = hb + 15761408;             // 16,384
  bf16* PEYb  = hb + 15777792;             // 16,384
  bf16* PEY1b = hb + 15794176;             // 16,384
  bf16* SAIWb = hb + 15810560;             // 2,359,296
  bf16* SAOWb = hb + 18169856;             // 393,216
  bf16* CAIWb = hb + 18563072;             // 1,179,648
  bf16* CAOWb = hb + 19742720;             // 196,608
  bf16* MW1b  = hb + 19939328;             // 196,608
  bf16* WFb   = hb + 20135936;             // 884,736
  bf16* W2b   = hb + 21020672;             // 589,824  [12][384][128] combined W

  bf16* QR   = QKV + 3145728;
  bf16* FL4F = QKV + 4194304;              // free at last layer -> raw3
  bf16* QR1  = QKV + 5767168;
  bf16* KVq  = QKV1;
  bf16* KVq1 = QKV1 + 2097152;
  bf16* XR2  = Xb;
  bf16* XR21 = Xb + 1048576;

  GArgs ga; int ng = 0; int gb = 0;
  auto gadd = [&](GDesc gd) { ga.cum[ng] = gb; ga.d[ng] = gd;
                              gb += ((gd.M + 63) >> 6) * (gd.N >> 6); ++ng; };
  auto gflush = [&]() { ga.nprob = ng;
                        k_gemm_multi<<<gb, 256, 0, stream>>>(ga); ng = 0; gb = 0; };
  LArgs la; int nl = 0; int lb = 0;
  auto lnadd = [&](LDesc ld) { la.cum[nl] = lb; la.d[nl] = ld;
                               lb += (ld.ntok + 3) / 4; ++nl; };
  auto lnflush = [&]() { la.nprob = nl;
                         k_ln_multi<<<lb, 256, 0, stream>>>(la); nl = 0; lb = 0; };
  AArgs aa; int na = 0; int ab = 0;
  auto aadd = [&](ADesc ad) { aa.cum[na] = ab; aa.d[na] = ad;
                              ab += ad.B * (ad.Wlen >> 4) * 2; ++na; };
  auto aflush = [&]() { aa.nprob = na;
                        k_attn_mfma<<<ab, 256, 0, stream>>>(aa); na = 0; ab = 0; };

  auto G = [&](const bf16* A, const bf16* W, const float* bias,
               bf16* Cb, float* Cf, const float* resid,
               int M, int N, int K, int lda, int scaleN,
               int imode, int iD0, int iD1,
               int omode, int oD0, int oD1, int ooff,
               const float* Af0 = nullptr, const float* Af1 = nullptr) {
    GDesc gd; gd.A = A; gd.Af0 = Af0; gd.Af1 = Af1; gd.W = W; gd.bias = bias;
    gd.Cb = Cb; gd.Cf = Cf; gd.resid = resid;
    gd.M = M; gd.N = N; gd.K = K; gd.lda = lda; gd.scaleN = scaleN;
    gd.imode = imode; gd.iD0 = iD0; gd.iD1 = iD1;
    gd.omode = omode; gd.oD0 = oD0; gd.oD1 = oD1; gd.ooff = ooff;
    gadd(gd);
  };
  auto AT = [&](const bf16* Q, int ldQ, const bf16* K, int ldK, const bf16* V, int ldV,
                const bf16* PPb, int Wlen, int B, int sflip, bf16* O) {
    ADesc ad; ad.Q = Q; ad.K = K; ad.V = V; ad.PPb = PPb; ad.O = O;
    ad.raw0 = nullptr; ad.raw1 = nullptr; ad.raw2 = nullptr; ad.raw3 = nullptr;
    ad.ldQ = ldQ; ad.ldK = ldK; ad.ldV = ldV; ad.Wlen = Wlen; ad.B = B;
    ad.sflip = sflip; ad.useMask = 0;
    aadd(ad);
  };

  {
    FArgs fa; int nf = 0; int fb = 0;
    auto fadd = [&](const float* s, bf16* dd, int n) {
      fa.cum[nf] = fb; fa.d[nf] = FDesc{s, dd, n}; fb += (n + 1023) / 1024; ++nf; };
    fadd(SA_IW, SAIWb, 6 * 4 * 384 * 128);
    fadd(SA_OW, SAOWb, 6 * 4 * 128 * 128);
    fadd(CA_IW, CAIWb, 6 * 2 * 384 * 128);
    fadd(CA_OW, CAOWb, 6 * 2 * 128 * 128);
    fadd(MW1,   MW1b,  6 * 128 * 256);
    fadd(PE,    PEb,   255 * 128);
    fadd(PE1,   PE1b,  127 * 128);
    fadd(PEY,   PEYb,  127 * 128);
    fadd(PEY1,  PEY1b, 127 * 128);
    fa.nprob = nf;
    k_f2b_multi<<<fb, 256, 0, stream>>>(fa);
  }
  k_wfullb<<<768, 128, 0, stream>>>(MW2, WFb);
  k_zero_guard<<<1, 256, 0, stream>>>(PP0b, PP1b);
  // combined W2 = iw_x @ ow_y  and  b2 = iw_x @ ob_y + ib_x  (12 problems)
  {
    WCArgs wc; BCArgs bc;
    for (int l = 0; l < 6; ++l) {
      for (int s = 0; s < 2; ++s) {
        int p = l * 2 + s;
        int iwi = (s == 0) ? 0 : 2;   // in-proj idx (x / x1)
        int owi = (s == 0) ? 1 : 3;   // out-proj idx (y / y1)
        wc.iw[p]  = SAIWb + (size_t)l * 4 * 384 * 128 + (size_t)iwi * 384 * 128;
        wc.ow[p]  = SAOWb + (size_t)l * 4 * 128 * 128 + (size_t)owi * 128 * 128;
        wc.out[p] = W2b + (size_t)p * 384 * 128;
        bc.iwf[p] = SA_IW + (size_t)l * 4 * 384 * 128 + (size_t)iwi * 384 * 128;
        bc.obf[p] = SA_OB + (size_t)l * 4 * 128 + (size_t)owi * 128;
        bc.ibf[p] = SA_IB + (size_t)l * 4 * 384 + (size_t)iwi * 384;
        bc.out[p] = B2f + (size_t)p * 384;
      }
    }
    k_wcomb<<<72, 256, 0, stream>>>(wc);
    k_bcomb<<<12, 384, 0, stream>>>(bc);
  }
  k_build_feat<<<16384, 128, 0, stream>>>(FLt, FRt, FEAT, 128);
  k_build_feat<<<8192, 128, 0, stream>>>(FL1t, FR1t, FEAT1, 64);

  for (int l = 0; l < 6; ++l) {
    bool last = (l == 5);
    const bf16* iw  = SAIWb + (size_t)l * 4 * 384 * 128;
    const float* ib = SA_IB + (size_t)l * 4 * 384;
    const bf16* ow  = SAOWb + (size_t)l * 4 * 128 * 128;
    const float* ob = SA_OB + (size_t)l * 4 * 128;
    const bf16* ciw  = CAIWb + (size_t)l * 2 * 384 * 128;
    const float* cib = CA_IB + (size_t)l * 2 * 384;
    const bf16* cow  = CAOWb + (size_t)l * 2 * 128 * 128;
    const float* cob = CA_OB + (size_t)l * 2 * 128;
    const bf16* ciw1 = ciw + 384 * 128;
    const float* cib1 = cib + 384;
    const bf16* cow1 = cow + 128 * 128;
    const float* cob1 = cob + 128;
    const int IW = 384 * 128, OW = 128 * 128;

    // ======================= SELF =======================
    lnadd(LDesc{FEAT, Xb, SA_N1G + l * 128, SA_N1B + l * 128, 16384, 128, 128, 0});
    if (!last) lnadd(LDesc{FEAT1, XBb, SA_N2G + l * 128, SA_N2B + l * 128, 8192, 128, 128, 0});
    lnflush();
    // y-qkv (ymap input) + y-pos projections
    G(Xb, iw + IW, ib + 384, QKV, nullptr, nullptr, 16384, 384, 128, 128, 128, 1, 128, 64, 0, 1, 1, 0);
    if (!last) G(XBb, iw + 3 * IW, ib + 3 * 384, QKV1, nullptr, nullptr, 8192, 384, 128, 128, 128, 1, 64, 64, 0, 1, 1, 0);
    G(PEYb, iw + IW, ib + 384, PP0b, nullptr, nullptr, 127, 256, 128, 128, 128, 0, 0, 0, 0, 1, 1, 0);
    if (!last) G(PEY1b, iw + 3 * IW, ib + 3 * 384, PP1b, nullptr, nullptr, 127, 256, 128, 128, 128, 0, 0, 0, 0, 1, 1, 0);
    gflush();
    // y-attention (output Ob in y-order)
    AT(QKV, 384, QKV + 128, 384, QKV + 256, 384, PP0b, 64, 256, 1, Ob);
    if (!last) AT(QKV1, 384, QKV1 + 128, 384, QKV1 + 256, 384, PP1b, 64, 128, 1, Ob1);
    aflush();
    // FUSED y-out-proj + x-qkv: QKV = Ob @ W2^T + b2 (inverse-ymap input)
    G(Ob, W2b + (size_t)(l * 2) * 49152, B2f + (l * 2) * 384, QKV, nullptr, nullptr,
      16384, 384, 128, 128, 128, 1, 64, 128, 0, 1, 1, 0);
    if (!last) G(Ob1, W2b + (size_t)(l * 2 + 1) * 49152, B2f + (l * 2 + 1) * 384, QKV1,
                 nullptr, nullptr, 8192, 384, 128, 128, 128, 1, 64, 64, 0, 1, 1, 0);
    G(PEb, iw, ib, PP0b, nullptr, nullptr, 255, 256, 128, 128, 128, 0, 0, 0, 0, 1, 1, 0);
    if (!last) G(PE1b, iw + 2 * IW, ib + 2 * 384, PP1b, nullptr, nullptr, 127, 256, 128, 128, 128, 0, 0, 0, 0, 1, 1, 0);
    gflush();
    AT(QKV, 384, QKV + 128, 384, QKV + 256, 384, PP0b, 128, 128, 1, Ob);
    if (!last) AT(QKV1, 384, QKV1 + 128, 384, QKV1 + 256, 384, PP1b, 64, 128, 1, Ob1);
    aflush();
    G(Ob, ow, ob, nullptr, FEAT, FEAT, 16384, 128, 128, 128, 0, 0, 0, 0, 0, 1, 1, 0);
    if (!last) G(Ob1, ow + 2 * OW, ob + 2 * 128, nullptr, FEAT1, FEAT1, 8192, 128, 128, 128, 0, 0, 0, 0, 0, 1, 1, 0);
    gflush();

    // ======================= CROSS =======================
    lnadd(LDesc{FEAT, Xb, CA_N1G + l * 128, CA_N1B + l * 128, 8192, 64, 128, 0});
    lnadd(LDesc{FEAT, Xb + 1048576, CA_N1G + l * 128, CA_N1B + l * 128, 8192, 64, 128, 64});
    if (!last) {
      lnadd(LDesc{FEAT1, XBb, CA_N2G + l * 128, CA_N2B + l * 128, 4096, 64, 128, 0});
      lnadd(LDesc{FEAT1, XBb + 524288, CA_N2G + l * 128, CA_N2B + l * 128, 4096, 64, 128, 64});
    }
    lnflush();
    G(Xb, ciw, cib, QKV, nullptr, nullptr, 8192, 384, 128, 128, 128, 0, 0, 0, 0, 1, 1, 0);
    G(Xb + 1048576, ciw, cib, QR, nullptr, nullptr, 8192, 128, 128, 128, 128, 0, 0, 0, 0, 1, 1, 0);
    if (!last) {
      G(XBb, ciw1, cib1, FL4F, nullptr, nullptr, 4096, 384, 128, 128, 128, 0, 0, 0, 0, 1, 1, 0);
      G(XBb + 524288, ciw1, cib1, QR1, nullptr, nullptr, 4096, 128, 128, 128, 128, 0, 0, 0, 0, 1, 1, 0);
    }
    G(PEb, ciw, cib, PP0b, nullptr, nullptr, 255, 256, 128, 128, 128, 0, 0, 0, 0, 1, 1, 0);
    if (!last) G(PE1b, ciw1, cib1, PP1b, nullptr, nullptr, 127, 256, 128, 128, 128, 0, 0, 0, 0, 1, 1, 0);
    gflush();
    AT(QR, 128, QKV + 128, 384, QKV + 256, 384, PP0b, 128, 64, -1, Ob);
    if (!last) AT(QR1, 128, FL4F + 128, 384, FL4F + 256, 384, PP1b, 64, 64, -1, Ob1);
    aflush();
    G(Ob, cow, cob, nullptr, FEAT, FEAT, 8192, 128, 128, 128, 0, 0, 0, 0, 0, 64, 128, 64);
    if (!last) G(Ob1, cow1, cob1, nullptr, FN2, FEAT1, 4096, 128, 128, 128, 0, 0, 0, 0, 0, 64, 128, 64);
    gflush();
    lnadd(LDesc{FEAT, XR2, CA_N1G + l * 128, CA_N1B + l * 128, 8192, 64, 128, 64});
    if (!last) lnadd(LDesc{FN2, XR21, CA_N2G + l * 128, CA_N2B + l * 128, 4096, 64, 128, 64});
    lnflush();
    G(XR2, ciw + 128 * 128, cib + 128, KVq, nullptr, nullptr, 8192, 256, 128, 128, 0, 0, 0, 0, 0, 1, 1, 0);
    if (!last) G(XR21, ciw1 + 128 * 128, cib1 + 128, KVq1, nullptr, nullptr, 4096, 256, 128, 128, 0, 0, 0, 0, 0, 1, 1, 0);
    gflush();
    if (last) {
      ADesc ad; ad.Q = QKV; ad.K = KVq; ad.V = KVq + 128; ad.PPb = PP0b;
      ad.O = nullptr;
      ad.raw0 = FEAT1; ad.raw1 = FN2; ad.raw2 = (float*)Ob; ad.raw3 = (float*)FL4F;
      ad.ldQ = 384; ad.ldK = 256; ad.ldV = 256;
      ad.Wlen = 128; ad.B = 64; ad.sflip = 1; ad.useMask = 1;
      k_attn_raw<<<64 * 8, 256, 0, stream>>>(ad);
      k_rawcomb4<<<4096, 256, 0, stream>>>(FEAT1, FN2, (float*)Ob, (float*)FL4F,
                                           (bf16*)d_out);
      break;
    }
    AT(QKV, 384, KVq, 256, KVq + 128, 256, PP0b, 128, 64, 1, Ob);
    AT(FL4F, 384, KVq1, 256, KVq1 + 128, 256, PP1b, 64, 64, 1, Ob1);
    aflush();
    G(Ob, cow, cob, nullptr, FEAT, FEAT, 8192, 128, 128, 128, 0, 0, 0, 0, 0, 64, 128, 0);
    G(Ob1, cow1, cob1, nullptr, FN2, FEAT1, 4096, 128, 128, 128, 0, 0, 0, 0, 0, 64, 128, 0);
    gflush();
    G(nullptr, MW1b + (size_t)l * 128 * 256, MB1 + l * 128, Ob, nullptr, nullptr,
      16384, 128, 256, 256, 0, 3, 0, 0, 0, 1, 1, 0, FN2, FEAT);
    gflush();
    G(Ob, WFb + (size_t)l * 128 * 1152, MB2 + l * 128, nullptr, FEAT, nullptr,
      16384, 128, 1152, 128, 0, 2, 0, 0, 0, 1, 1, 0);
    gflush();
  }
}

// Round 16
// 1593.242 us; speedup vs baseline: 1.0157x; 1.0157x over previous
//
#include <hip/hip_runtime.h>
#include <hip/hip_bf16.h>
#include <math.h>

// ---------------------------------------------------------------------------
// N=1, C=128, H=64, W=128, W1=64, HN=64, 2HN=128, NH=8, hd=16, L=6.
// GEMM 64x64 tiles; attention on MFMA (block = b/strip/half, wave = head),
// dynamic-LDS with compile-time strides (Wlen64 launches: 23.5KB -> 6 blk/CU).
// y-out-proj + x-qkv folded via precomputed W2 = iw_x @ ow_y.
// Last-layer raw scores: in-block 4-wave reduce -> d_out directly.
// ---------------------------------------------------------------------------

typedef __attribute__((ext_vector_type(8))) short bf16x8;
typedef __attribute__((ext_vector_type(4))) float f32x4;
typedef __hip_bfloat16 bf16;

__device__ __forceinline__ float b2f(unsigned short u) {
  return __uint_as_float((unsigned)u << 16);
}
__device__ __forceinline__ short f2bs(float x) {
  bf16 h = __float2bfloat16(x);
  short s;
  __builtin_memcpy(&s, &h, 2);
  return s;
}
__device__ __forceinline__ int ymap(int t, int D0, int D1) {
  return (t % D0) * (2 * D1) + ((t / D0) & 1) * D1 + t / (2 * D0);
}

// ============================= small setup kernels ==========================

__global__ void k_build_feat(const float* __restrict__ L, const float* __restrict__ R,
                             float* __restrict__ feat, int W) {
  int t = blockIdx.x;
  int c = threadIdx.x;
  int b = t & 127;
  int w = t >> 7;
  const float* src = (b < 64) ? L : R;
  int h = b & 63;
  feat[(size_t)t * 128 + c] = src[((size_t)c * 64 + h) * W + w];
}

struct FDesc { const float* s; bf16* d; int n; };
struct FArgs { FDesc d[9]; int cum[10]; int nprob; };
__global__ void k_f2b_multi(FArgs fa) {
  int bid = blockIdx.x;
  int p = 0;
  while (p + 1 < fa.nprob && bid >= fa.cum[p + 1]) ++p;
  const FDesc d = fa.d[p];
  int i = (bid - fa.cum[p]) * 1024 + threadIdx.x * 4;
  if (i + 3 < d.n) {
    float4 x = *(const float4*)(d.s + i);
    d.d[i + 0] = __float2bfloat16(x.x);
    d.d[i + 1] = __float2bfloat16(x.y);
    d.d[i + 2] = __float2bfloat16(x.z);
    d.d[i + 3] = __float2bfloat16(x.w);
  } else {
    for (int z = 0; z < 4 && i + z < d.n; ++z) d.d[i + z] = __float2bfloat16(d.s[i + z]);
  }
}

__global__ void k_wfullb(const float* __restrict__ w2, bf16* __restrict__ wf) {
  int bid = blockIdx.x;
  int l = bid >> 7, co = bid & 127;
  int ci = threadIdx.x;
  const float* src = w2 + (size_t)l * 128 * 128 * 9;
  bf16* dst = wf + (size_t)l * 128 * 1152;
#pragma unroll
  for (int ky = 0; ky < 3; ky++)
#pragma unroll
    for (int kx = 0; kx < 3; kx++)
      dst[(size_t)co * 1152 + (kx * 3 + ky) * 128 + ci] =
          __float2bfloat16(src[((size_t)(co * 128 + ci) * 3 + ky) * 3 + kx]);
}

// zero guard rows of the pos tables
__global__ void k_zero_guard(bf16* p0, bf16* p1) {
  int t = threadIdx.x;
  p0[255 * 256 + t] = __float2bfloat16(0.0f);
  p1[127 * 256 + t] = __float2bfloat16(0.0f);
}

// combined weights W2[p][j][c] = sum_t iw[p][j][t] * ow[p][t][c]
struct WCArgs { const bf16* iw[12]; const bf16* ow[12]; bf16* out[12]; };
__global__ __launch_bounds__(256) void k_wcomb(WCArgs a) {
  __shared__ bf16 sOw[128 * 128];
  int p = blockIdx.x / 6, rc = blockIdx.x % 6;
  const bf16* iw = a.iw[p];
  const bf16* ow = a.ow[p];
  for (int i = threadIdx.x; i < 128 * 16; i += 256)
    ((bf16x8*)sOw)[i] = ((const bf16x8*)ow)[i];
  __syncthreads();
  int row = rc * 64 + (threadIdx.x >> 2);
  int seg = (threadIdx.x & 3) * 32;
  float acc[32];
#pragma unroll
  for (int c = 0; c < 32; ++c) acc[c] = 0.f;
  for (int t = 0; t < 128; ++t) {
    float av = b2f((unsigned short)iw[row * 128 + t]);
#pragma unroll
    for (int c = 0; c < 32; ++c)
      acc[c] = fmaf(av, b2f((unsigned short)sOw[t * 128 + seg + c]), acc[c]);
  }
  bf16* o = a.out[p] + (size_t)row * 128 + seg;
  for (int c = 0; c < 32; ++c) o[c] = __float2bfloat16(acc[c]);
}

// combined bias b2[p][j] = sum_t iw_f32[p][j][t]*ob[p][t] + ib[p][j]
struct BCArgs { const float* iwf[12]; const float* obf[12]; const float* ibf[12]; float* out[12]; };
__global__ void k_bcomb(BCArgs a) {
  int p = blockIdx.x, j = threadIdx.x;   // 384 threads
  const float* iw = a.iwf[p] + (size_t)j * 128;
  const float* ob = a.obf[p];
  float acc = a.ibf[p][j];
  for (int t = 0; t < 128; ++t) acc = fmaf(iw[t], ob[t], acc);
  a.out[p][j] = acc;
}

// ============================= LN multi =====================================

struct LDesc { const float* src; bf16* dst; const float* g; const float* be;
               int ntok, Bout, PBin, offIn; };
struct LArgs { LDesc d[4]; int cum[5]; int nprob; };

__global__ __launch_bounds__(256) void k_ln_multi(LArgs la) {
  int bid = blockIdx.x;
  int p = 0;
  while (p + 1 < la.nprob && bid >= la.cum[p + 1]) ++p;
  const LDesc d = la.d[p];
  int t = (bid - la.cum[p]) * 4 + (threadIdx.x >> 6);
  int lane = threadIdx.x & 63;
  if (t >= d.ntok) return;
  int w = t / d.Bout, b = t - w * d.Bout;
  const float* row = d.src + (size_t)(w * d.PBin + d.offIn + b) * 128;
  float x0 = row[lane], x1 = row[lane + 64];
  float s = x0 + x1;
#pragma unroll
  for (int o = 32; o; o >>= 1) s += __shfl_xor(s, o, 64);
  float m = s * (1.0f / 128.0f);
  float d0 = x0 - m, d1 = x1 - m;
  float v = d0 * d0 + d1 * d1;
#pragma unroll
  for (int o = 32; o; o >>= 1) v += __shfl_xor(v, o, 64);
  float r = 1.0f / sqrtf(v * (1.0f / 128.0f) + 1e-5f);
  bf16* orow = d.dst + (size_t)t * 128;
  orow[lane]      = __float2bfloat16(d0 * r * d.g[lane]      + d.be[lane]);
  orow[lane + 64] = __float2bfloat16(d1 * r * d.g[lane + 64] + d.be[lane + 64]);
}

// ============================= GEMM multi (64x64 tiles) =====================

struct GDesc {
  const bf16* A; const float* Af0; const float* Af1;
  const bf16* W; const float* bias;
  bf16* Cb; float* Cf; const float* resid;
  int M, N, K, lda, scaleN;
  int imode, iD0, iD1;
  int omode, oD0, oD1, ooff;
};
struct GArgs { GDesc d[6]; int cum[7]; int nprob; };

__global__ __launch_bounds__(256) void k_gemm_multi(GArgs ga) {
  __shared__ bf16x8 sA[64 * 4];
  __shared__ bf16x8 sB[64 * 4];
  int bid = blockIdx.x;
  int p = 0;
  while (p + 1 < ga.nprob && bid >= ga.cum[p + 1]) ++p;
  const GDesc d = ga.d[p];
  int local = bid - ga.cum[p];
  int tilesx = d.N >> 6;
  int ty = local / tilesx, tx = local - ty * tilesx;
  const int m0 = ty << 6, n0 = tx << 6;
  const int tid = threadIdx.x;
  const int lane = tid & 63;
  const int wave = tid >> 6;
  const int wm = wave >> 1, wn = wave & 1;
  const int fr = lane & 15;
  const int kc = lane >> 4;
  f32x4 acc[2][2];
#pragma unroll
  for (int f = 0; f < 2; f++)
#pragma unroll
    for (int g = 0; g < 2; g++) acc[f][g] = (f32x4){0.f, 0.f, 0.f, 0.f};

  for (int k0 = 0; k0 < d.K; k0 += 32) {
    {
      int row = tid >> 2, ch = tid & 3;
      int m = m0 + row;
      bf16x8 val = (bf16x8){0, 0, 0, 0, 0, 0, 0, 0};
      if (d.imode == 0) {
        if (m < d.M) val = *(const bf16x8*)(d.A + (size_t)m * d.lda + k0 + ch * 8);
      } else if (d.imode == 1) {
        if (m < d.M) {
          int ar = ymap(m, d.iD0, d.iD1);
          val = *(const bf16x8*)(d.A + (size_t)ar * d.lda + k0 + ch * 8);
        }
      } else if (d.imode == 2) {
        int kblk = k0 >> 7;
        int kx = kblk / 3, ky = kblk - kx * 3;
        int arow = m + (kx - 1) * 128;
        int y = (m & 127) + (ky - 1);
        if (arow >= 0 && arow < d.M && y >= 0 && y < 128)
          val = *(const bf16x8*)(d.A + (size_t)arow * d.lda + (k0 & 127) + ch * 8);
      } else {
        int kk = k0 + ch * 8;
        int w = m >> 7, y = m & 127;
        if (kk < 128) {
          float xo = fminf(fmaxf(w * 0.5f - 0.25f, 0.0f), 63.0f);
          int lo = (int)xo;
          int hi = (lo + 1 < 63) ? lo + 1 : 63;
          float f = xo - (float)lo;
          const float* a0 = d.Af0 + ((size_t)lo * 128 + y) * 128 + kk;
          const float* a1 = d.Af0 + ((size_t)hi * 128 + y) * 128 + kk;
#pragma unroll
          for (int z = 0; z < 8; ++z) val[z] = f2bs(a0[z] * (1.0f - f) + a1[z] * f);
        } else {
          const float* a0 = d.Af1 + (size_t)m * 128 + (kk - 128);
#pragma unroll
          for (int z = 0; z < 8; ++z) val[z] = f2bs(a0[z]);
        }
      }
      sA[row * 4 + (ch ^ ((row >> 2) & 3))] = val;
      bf16x8 bval = *(const bf16x8*)(d.W + (size_t)(n0 + row) * d.K + k0 + ch * 8);
      sB[row * 4 + (ch ^ ((row >> 2) & 3))] = bval;
    }
    __syncthreads();
    bf16x8 af[2], bg[2];
#pragma unroll
    for (int f = 0; f < 2; ++f) {
      int row = wm * 32 + f * 16 + fr;
      af[f] = sA[row * 4 + (kc ^ ((row >> 2) & 3))];
    }
#pragma unroll
    for (int g = 0; g < 2; ++g) {
      int row = wn * 32 + g * 16 + fr;
      bg[g] = sB[row * 4 + (kc ^ ((row >> 2) & 3))];
    }
#pragma unroll
    for (int f = 0; f < 2; ++f)
#pragma unroll
      for (int g = 0; g < 2; ++g)
        acc[f][g] = __builtin_amdgcn_mfma_f32_16x16x32_bf16(af[f], bg[g], acc[f][g], 0, 0, 0);
    __syncthreads();
  }
  const int r4 = (lane >> 4) << 2;
  const int ocol = lane & 15;
#pragma unroll
  for (int f = 0; f < 2; ++f) {
#pragma unroll
    for (int g = 0; g < 2; ++g) {
      int n = n0 + wn * 32 + g * 16 + ocol;
      float bv = d.bias ? d.bias[n] : 0.0f;
      bool sc = (n < d.scaleN);
#pragma unroll
      for (int i = 0; i < 4; ++i) {
        int m = m0 + wm * 32 + f * 16 + r4 + i;
        if (m < d.M) {
          int row;
          if (d.omode == 0) row = (m / d.oD0) * d.oD1 + d.ooff + (m % d.oD0);
          else row = ymap(m, d.oD0, d.oD1);
          size_t idx = (size_t)row * d.N + n;
          float val = acc[f][g][i] + bv;
          if (sc) val *= 0.25f;
          if (d.resid) val += d.resid[idx];
          if (d.Cb) d.Cb[idx] = __float2bfloat16(val);
          else d.Cf[idx] = val;
        }
      }
    }
  }
}

// ============================= attention (MFMA) =============================
// Dynamic LDS, compile-time strides PST=WLEN+8:
//   Vt [64][PST] | Pl [4*16][PST] | T2l [4*16*20] | Ost [16*80]
// Wlen=64 launches: 23.5KB -> 6 blocks/CU; Wlen=128: 39.9KB -> 4 blocks/CU.

struct ADesc {
  const bf16* Q; const bf16* K; const bf16* V;
  const bf16* PPb; bf16* O;
  int ldQ, ldK, ldV, Wlen, B, sflip, useMask;
};
struct AArgs { ADesc d[2]; int cum[3]; int nprob; };

template<int WLEN, int SGN>
__device__ __forceinline__ void attn_core(const ADesc& d, int b, int st, int h,
                                          int tid, bf16* smem) {
  constexpr int NT = WLEN / 16;
  constexpr int R = WLEN - 1;
  constexpr int PST = WLEN + 8;
  const f32x4 z4 = (f32x4){0.f, 0.f, 0.f, 0.f};
  const bf16x8 zb = (bf16x8){0, 0, 0, 0, 0, 0, 0, 0};
  bf16* Vt  = smem;                    // [64][PST]
  bf16* Pl  = smem + 64 * PST;         // [64][PST]
  bf16* T2l = smem + 128 * PST;        // [4][16][20]
  bf16* Ost = T2l + 1280;              // [16][80]

  // ---- stage V^T (64 channel-rows of this half) [c][v], stride PST ----
  {
    int q = tid & (WLEN / 2 - 1);
    int cc = tid >> ((WLEN == 128) ? 6 : 5);
    constexpr int CH = (WLEN == 128) ? 16 : 8;
    int cb = cc * CH;
    const bf16* v0p = d.V + ((size_t)(2 * q) * d.B + b) * d.ldV + h * 64 + cb;
    const bf16* v1p = d.V + ((size_t)(2 * q + 1) * d.B + b) * d.ldV + h * 64 + cb;
#pragma unroll
    for (int j = 0; j < CH; j += 8) {
      bf16x8 a = *(const bf16x8*)(v0p + j);
      bf16x8 bb = *(const bf16x8*)(v1p + j);
#pragma unroll
      for (int z = 0; z < 8; ++z) {
        unsigned pk = (unsigned)(unsigned short)a[z] |
                      ((unsigned)(unsigned short)bb[z] << 16);
        *(unsigned*)(Vt + (size_t)(cb + j + z) * PST + 2 * q) = pk;
      }
    }
  }
  __syncthreads();

  const int wave = tid >> 6, l = tid & 63;
  const int lm = l & 15, lg = l >> 4;
  const bool zlane = (lg >= 2);
  bf16* Pw  = Pl + wave * (16 * PST);
  bf16* T2w = T2l + wave * (16 * 20);
  int p0[4], src[4], hi[4], tsel[4];
  bool csel[4];
#pragma unroll
  for (int i = 0; i < 4; ++i) {
    p0[i] = SGN * (lm - 4 * lg - i) + 15;
    src[i] = (l & 48) | (p0[i] & 15);
    hi[i] = p0[i] & 16;
    if (SGN == 1) {
      int t0 = lm + 15 - 4 * lg - i;
      csel[i] = (t0 < 16);
      tsel[i] = csel[i] ? t0 : t0 - 16;
    } else {
      int t0 = lm - 15 + 4 * lg + i;
      csel[i] = (t0 >= 0);
      tsel[i] = csel[i] ? t0 : t0 + 16;
    }
  }

  const int w0 = st * 16;
  const int chb = h * 64 + wave * 16 + lg * 8;

  bf16x8 qf = zb;
  if (!zlane) qf = *(const bf16x8*)(d.Q + ((size_t)(w0 + lm) * d.B + b) * d.ldQ + chb);

  const int U0 = (SGN == 1) ? (R - w0 - 15) : (R + w0 - WLEN + 1);
  const int Ub0 = (SGN == 1) ? (R - w0 - 15) : (R - (WLEN - 16) + w0 - 15);
  const bf16* t1p = d.PPb + (size_t)(U0 + lm) * 256 + 128 + chb;
  const bf16* t2p = d.PPb + (size_t)(Ub0 + lm) * 256 + chb;
  const int v0i = ((SGN == 1) ? 0 : (WLEN - 16)) + lm;
  const bf16* kp = d.K + ((size_t)v0i * d.B + b) * d.ldK + chb;
  const ptrdiff_t kstep = (ptrdiff_t)SGN * 16 * d.B * d.ldK;

  f32x4 t1a;
  {
    bf16x8 z = zb;
    if (!zlane) z = *(const bf16x8*)t1p;
    t1p += 16 * 256;
    t1a = __builtin_amdgcn_mfma_f32_16x16x32_bf16(qf, z, z4, 0, 0, 0);
  }
  int v = v0i;
#pragma unroll
  for (int j = 0; j < NT; ++j) {
    f32x4 t1b;
    {
      bf16x8 z = zb;
      if (!zlane) z = *(const bf16x8*)t1p;
      t1p += 16 * 256;
      t1b = __builtin_amdgcn_mfma_f32_16x16x32_bf16(qf, z, z4, 0, 0, 0);
    }
    bf16x8 kf = zb;
    if (!zlane) kf = *(const bf16x8*)kp;
    kp += kstep;
    f32x4 s4 = __builtin_amdgcn_mfma_f32_16x16x32_bf16(qf, kf, z4, 0, 0, 0);
    bf16x8 zA = zb, zB = zb;
    if (!zlane) {
      zA = *(const bf16x8*)t2p;
      zB = *(const bf16x8*)(t2p + 16 * 256);
    }
    t2p += 16 * 256;
    f32x4 t2A = __builtin_amdgcn_mfma_f32_16x16x32_bf16(zA, kf, z4, 0, 0, 0);
    f32x4 t2B = __builtin_amdgcn_mfma_f32_16x16x32_bf16(zB, kf, z4, 0, 0, 0);
#pragma unroll
    for (int i = 0; i < 4; ++i)
      T2w[lm * 20 + tsel[i]] = f2bs(csel[i] ? t2A[i] : t2B[i]);
    ushort4 t2u = *(const ushort4*)(T2w + lm * 20 + 4 * lg);
    unsigned short t2a[4] = {t2u.x, t2u.y, t2u.z, t2u.w};
#pragma unroll
    for (int i = 0; i < 4; ++i) {
      float va = __shfl(t1a[i], src[i], 64);
      float vb = __shfl(t1b[i], src[i], 64);
      float s = s4[i] + (hi[i] ? vb : va) + b2f(t2a[i]);
      Pw[(4 * lg + i) * PST + v] = f2bs(__expf(s));
    }
    t1a = t1b;
    v += SGN * 16;
  }
  const bf16x8 ones = (bf16x8){0x3F80, 0x3F80, 0x3F80, 0x3F80,
                               0x3F80, 0x3F80, 0x3F80, 0x3F80};
  f32x4 oa = z4, rsm = z4;
#pragma unroll
  for (int vc = 0; vc < NT / 2; ++vc) {
    bf16x8 pf = *(const bf16x8*)(Pw + lm * PST + vc * 32 + lg * 8);
    bf16x8 vf = *(const bf16x8*)(Vt + (size_t)(wave * 16 + lm) * PST + vc * 32 + lg * 8);
    oa = __builtin_amdgcn_mfma_f32_16x16x32_bf16(pf, vf, oa, 0, 0, 0);
    rsm = __builtin_amdgcn_mfma_f32_16x16x32_bf16(pf, ones, rsm, 0, 0, 0);
  }
#pragma unroll
  for (int i = 0; i < 4; ++i)
    Ost[(4 * lg + i) * 80 + wave * 16 + lm] = f2bs(oa[i] / rsm[i]);
  __syncthreads();
  if (tid < 128) {
    int row = tid >> 3, ch8 = (tid & 7) * 8;
    bf16x8 vv = *(const bf16x8*)(Ost + row * 80 + ch8);
    *(bf16x8*)(d.O + ((size_t)(w0 + row) * d.B + b) * 128 + h * 64 + ch8) = vv;
  }
}

__global__ __launch_bounds__(256, 4) void k_attn_mfma(AArgs aa) {
  extern __shared__ bf16 smem[];
  int bid = blockIdx.x;
  int p = 0;
  while (p + 1 < aa.nprob && bid >= aa.cum[p + 1]) ++p;
  const ADesc d = aa.d[p];
  int local = bid - aa.cum[p];
  int b = local % d.B;
  int rest = local / d.B;
  int ns = d.Wlen >> 4;
  int st = rest % ns, h = rest / ns;
  int tid = threadIdx.x;
  if (d.Wlen == 128) {
    if (d.sflip == 1) attn_core<128, 1>(d, b, st, h, tid, smem);
    else attn_core<128, -1>(d, b, st, h, tid, smem);
  } else {
    if (d.sflip == 1) attn_core<64, 1>(d, b, st, h, tid, smem);
    else attn_core<64, -1>(d, b, st, h, tid, smem);
  }
}

// Raw-score kernel (last layer): WLEN=128, SGN=1, causal mask, no O/softmax.
// 4 waves' head-pair partials reduced in LDS; masked bf16 written to d.O.
__global__ __launch_bounds__(256, 2) void k_attn_raw(ADesc d) {
  __shared__ bf16 T2l[4 * 16 * 20];
  __shared__ float Rl[4][16][128];
  constexpr int NT = 8;
  constexpr int R = 127;
  const f32x4 z4 = (f32x4){0.f, 0.f, 0.f, 0.f};
  const bf16x8 zb = (bf16x8){0, 0, 0, 0, 0, 0, 0, 0};
  int bid = blockIdx.x;
  int b = bid % d.B, st = bid / d.B;
  int tid = threadIdx.x;
  const int wave = tid >> 6, l = tid & 63;
  const int lm = l & 15, lg = l >> 4;
  const bool zlane = (lg >= 2);
  bf16* T2w = T2l + wave * (16 * 20);
  int p0[4];
#pragma unroll
  for (int i = 0; i < 4; ++i) p0[i] = (lm - 4 * lg - i) + 15;
  const int w0 = st * 16;
  f32x4 raw[NT];
#pragma unroll
  for (int vt = 0; vt < NT; ++vt) raw[vt] = z4;

  for (int hh = 0; hh < 2; ++hh) {
    const int e = wave * 2 + hh;
    const int chb = e * 16 + lg * 8;
    bf16x8 qf = zb;
    if (!zlane) qf = *(const bf16x8*)(d.Q + ((size_t)(w0 + lm) * d.B + b) * d.ldQ + chb);
    const int U0 = R - w0 - 15;
    f32x4 t1a;
    {
      int u = min(max(U0 + lm, 0), 2 * R);
      bf16x8 z = zb;
      if (!zlane) z = *(const bf16x8*)(d.PPb + (size_t)u * 256 + 128 + chb);
      t1a = __builtin_amdgcn_mfma_f32_16x16x32_bf16(qf, z, z4, 0, 0, 0);
    }
#pragma unroll
    for (int j = 0; j < NT; ++j) {
      const int vt = j;
      const int v = vt * 16 + lm;
      f32x4 t1b;
      {
        int u = min(max(U0 + (j + 1) * 16 + lm, 0), 2 * R);
        bf16x8 z = zb;
        if (!zlane) z = *(const bf16x8*)(d.PPb + (size_t)u * 256 + 128 + chb);
        t1b = __builtin_amdgcn_mfma_f32_16x16x32_bf16(qf, z, z4, 0, 0, 0);
      }
      bf16x8 kf = zb;
      if (!zlane) kf = *(const bf16x8*)(d.K + ((size_t)v * d.B + b) * d.ldK + chb);
      f32x4 s4 = __builtin_amdgcn_mfma_f32_16x16x32_bf16(qf, kf, z4, 0, 0, 0);
      const int Ub = R + vt * 16 - w0 - 15;
#pragma unroll
      for (int u2 = 0; u2 < 2; ++u2) {
        int ua = min(max(Ub + u2 * 16 + lm, 0), 2 * R);
        bf16x8 z = zb;
        if (!zlane) z = *(const bf16x8*)(d.PPb + (size_t)ua * 256 + chb);
        f32x4 t2 = __builtin_amdgcn_mfma_f32_16x16x32_bf16(z, kf, z4, 0, 0, 0);
#pragma unroll
        for (int i = 0; i < 4; ++i) {
          int u = Ub + u2 * 16 + 4 * lg + i;
          int t = R + v - u - w0;
          if (t >= 0 && t < 16) T2w[lm * 20 + t] = f2bs(t2[i]);
        }
      }
      ushort4 t2u = *(const ushort4*)(T2w + lm * 20 + 4 * lg);
      unsigned short t2a[4] = {t2u.x, t2u.y, t2u.z, t2u.w};
#pragma unroll
      for (int i = 0; i < 4; ++i) {
        int src = (l & 48) | (p0[i] & 15);
        float va = __shfl(t1a[i], src, 64);
        float vb = __shfl(t1b[i], src, 64);
        float s = s4[i] + ((p0[i] & 16) ? vb : va) + b2f(t2a[i]);
        if (v > (w0 + 4 * lg + i)) s = -INFINITY;
        raw[vt][i] += s;
      }
      t1a = t1b;
    }
  }
  // in-block reduce across the 4 waves (8 heads) -> masked bf16 to d.O
#pragma unroll
  for (int vt = 0; vt < NT; ++vt)
#pragma unroll
    for (int i = 0; i < 4; ++i)
      Rl[wave][4 * lg + i][vt * 16 + lm] = raw[vt][i];
  __syncthreads();
  {
    int r = tid >> 4, v8 = (tid & 15) * 8;
    int w = w0 + r;
    bf16* out = d.O + ((size_t)b * 128 + w) * 128;
#pragma unroll
    for (int z = 0; z < 8; ++z) {
      int vv = v8 + z;
      float sum = Rl[0][r][vv] + Rl[1][r][vv] + Rl[2][r][vv] + Rl[3][r][vv];
      out[vv] = __float2bfloat16((vv > w) ? 0.0f : sum);
    }
  }
}

// ============================= host =========================================

extern "C" void kernel_launch(void* const* d_in, const int* in_sizes, int n_in,
                              void* d_out, int out_size, void* d_ws, size_t ws_size,
                              hipStream_t stream) {
  (void)in_sizes; (void)n_in; (void)out_size; (void)ws_size;
  const float* FLt  = (const float*)d_in[0];
  const float* FRt  = (const float*)d_in[1];
  const float* FL1t = (const float*)d_in[2];
  const float* FR1t = (const float*)d_in[3];
  const float* PE   = (const float*)d_in[4];
  const float* PE1  = (const float*)d_in[5];
  const float* PEY  = (const float*)d_in[6];
  const float* PEY1 = (const float*)d_in[7];
  const float* SA_IW = (const float*)d_in[8];
  const float* SA_IB = (const float*)d_in[9];
  const float* SA_OW = (const float*)d_in[10];
  const float* SA_OB = (const float*)d_in[11];
  const float* SA_N1G = (const float*)d_in[12];
  const float* SA_N1B = (const float*)d_in[13];
  const float* SA_N2G = (const float*)d_in[14];
  const float* SA_N2B = (const float*)d_in[15];
  const float* CA_IW = (const float*)d_in[16];
  const float* CA_IB = (const float*)d_in[17];
  const float* CA_OW = (const float*)d_in[18];
  const float* CA_OB = (const float*)d_in[19];
  const float* CA_N1G = (const float*)d_in[20];
  const float* CA_N1B = (const float*)d_in[21];
  const float* CA_N2G = (const float*)d_in[22];
  const float* CA_N2B = (const float*)d_in[23];
  const float* MW1 = (const float*)d_in[24];
  const float* MB1 = (const float*)d_in[25];
  const float* MW2 = (const float*)d_in[26];
  const float* MB2 = (const float*)d_in[27];

  float* ws = (float*)d_ws;
  float* FEAT  = ws;                       // [16384,128]
  float* FEAT1 = ws + 2097152;             // [8192,128]
  float* FN2   = ws + 3145728;             // [8192,128]
  bf16* PP0b   = (bf16*)(ws + 4194304);    // [256,256] bf16 (row 255 = guard)
  bf16* PP1b   = (bf16*)(ws + 4259840);    // [128,256] bf16 (row 127 = guard)
  float* B2f   = ws + 4276224;             // [12][384] fp32 combined bias
  bf16* hb = (bf16*)(ws + 4292608);
  bf16* QKV   = hb;                        // 6,291,456
  bf16* QKV1  = hb + 6291456;              // 3,145,728
  bf16* Xb    = hb + 9437184;              // 2,097,152
  bf16* XBb   = hb + 11534336;             // 1,048,576
  bf16* Ob    = hb + 12582912;             // 2,097,152
  bf16* Ob1   = hb + 14680064;             // 1,048,576
  bf16* PEb   = hb + 15728640;             // 32,768
  bf16* PE1b  = hb + 15761408;             // 16,384
  bf16* PEYb  = hb + 15777792;             // 16,384
  bf16* PEY1b = hb + 15794176;             // 16,384
  bf16* SAIWb = hb + 15810560;             // 2,359,296
  bf16* SAOWb = hb + 18169856;             // 393,216
  bf16* CAIWb = hb + 18563072;             // 1,179,648
  bf16* CAOWb = hb + 19742720;             // 196,608
  bf16* MW1b  = hb + 19939328;             // 196,608
  bf16* WFb   = hb + 20135936;             // 884,736
  bf16* W2b   = hb + 21020672;             // 589,824  [12][384][128] combined W

  bf16* QR   = QKV + 3145728;
  bf16* FL4F = QKV + 4194304;
  bf16* QR1  = QKV + 5767168;
  bf16* KVq  = QKV1;
  bf16* KVq1 = QKV1 + 2097152;
  bf16* XR2  = Xb;
  bf16* XR21 = Xb + 1048576;

  GArgs ga; int ng = 0; int gb = 0;
  auto gadd = [&](GDesc gd) { ga.cum[ng] = gb; ga.d[ng] = gd;
                              gb += ((gd.M + 63) >> 6) * (gd.N >> 6); ++ng; };
  auto gflush = [&]() { ga.nprob = ng;
                        k_gemm_multi<<<gb, 256, 0, stream>>>(ga); ng = 0; gb = 0; };
  LArgs la; int nl = 0; int lb = 0;
  auto lnadd = [&](LDesc ld) { la.cum[nl] = lb; la.d[nl] = ld;
                               lb += (ld.ntok + 3) / 4; ++nl; };
  auto lnflush = [&]() { la.nprob = nl;
                         k_ln_multi<<<lb, 256, 0, stream>>>(la); nl = 0; lb = 0; };
  AArgs aa; int na = 0; int ab = 0; int maxw = 0;
  auto aadd = [&](ADesc ad) { aa.cum[na] = ab; aa.d[na] = ad;
                              ab += ad.B * (ad.Wlen >> 4) * 2;
                              if (ad.Wlen > maxw) maxw = ad.Wlen; ++na; };
  auto aflush = [&]() { aa.nprob = na;
                        size_t sh = (size_t)(128 * (maxw + 8) + 2560) * 2;
                        k_attn_mfma<<<ab, 256, sh, stream>>>(aa);
                        na = 0; ab = 0; maxw = 0; };

  auto G = [&](const bf16* A, const bf16* W, const float* bias,
               bf16* Cb, float* Cf, const float* resid,
               int M, int N, int K, int lda, int scaleN,
               int imode, int iD0, int iD1,
               int omode, int oD0, int oD1, int ooff,
               const float* Af0 = nullptr, const float* Af1 = nullptr) {
    GDesc gd; gd.A = A; gd.Af0 = Af0; gd.Af1 = Af1; gd.W = W; gd.bias = bias;
    gd.Cb = Cb; gd.Cf = Cf; gd.resid = resid;
    gd.M = M; gd.N = N; gd.K = K; gd.lda = lda; gd.scaleN = scaleN;
    gd.imode = imode; gd.iD0 = iD0; gd.iD1 = iD1;
    gd.omode = omode; gd.oD0 = oD0; gd.oD1 = oD1; gd.ooff = ooff;
    gadd(gd);
  };
  auto AT = [&](const bf16* Q, int ldQ, const bf16* K, int ldK, const bf16* V, int ldV,
                const bf16* PPb, int Wlen, int B, int sflip, bf16* O) {
    ADesc ad; ad.Q = Q; ad.K = K; ad.V = V; ad.PPb = PPb; ad.O = O;
    ad.ldQ = ldQ; ad.ldK = ldK; ad.ldV = ldV; ad.Wlen = Wlen; ad.B = B;
    ad.sflip = sflip; ad.useMask = 0;
    aadd(ad);
  };

  {
    FArgs fa; int nf = 0; int fb = 0;
    auto fadd = [&](const float* s, bf16* dd, int n) {
      fa.cum[nf] = fb; fa.d[nf] = FDesc{s, dd, n}; fb += (n + 1023) / 1024; ++nf; };
    fadd(SA_IW, SAIWb, 6 * 4 * 384 * 128);
    fadd(SA_OW, SAOWb, 6 * 4 * 128 * 128);
    fadd(CA_IW, CAIWb, 6 * 2 * 384 * 128);
    fadd(CA_OW, CAOWb, 6 * 2 * 128 * 128);
    fadd(MW1,   MW1b,  6 * 128 * 256);
    fadd(PE,    PEb,   255 * 128);
    fadd(PE1,   PE1b,  127 * 128);
    fadd(PEY,   PEYb,  127 * 128);
    fadd(PEY1,  PEY1b, 127 * 128);
    fa.nprob = nf;
    k_f2b_multi<<<fb, 256, 0, stream>>>(fa);
  }
  k_wfullb<<<768, 128, 0, stream>>>(MW2, WFb);
  k_zero_guard<<<1, 256, 0, stream>>>(PP0b, PP1b);
  {
    WCArgs wc; BCArgs bc;
    for (int l = 0; l < 6; ++l) {
      for (int s = 0; s < 2; ++s) {
        int p = l * 2 + s;
        int iwi = (s == 0) ? 0 : 2;
        int owi = (s == 0) ? 1 : 3;
        wc.iw[p]  = SAIWb + (size_t)l * 4 * 384 * 128 + (size_t)iwi * 384 * 128;
        wc.ow[p]  = SAOWb + (size_t)l * 4 * 128 * 128 + (size_t)owi * 128 * 128;
        wc.out[p] = W2b + (size_t)p * 384 * 128;
        bc.iwf[p] = SA_IW + (size_t)l * 4 * 384 * 128 + (size_t)iwi * 384 * 128;
        bc.obf[p] = SA_OB + (size_t)l * 4 * 128 + (size_t)owi * 128;
        bc.ibf[p] = SA_IB + (size_t)l * 4 * 384 + (size_t)iwi * 384;
        bc.out[p] = B2f + (size_t)p * 384;
      }
    }
    k_wcomb<<<72, 256, 0, stream>>>(wc);
    k_bcomb<<<12, 384, 0, stream>>>(bc);
  }
  k_build_feat<<<16384, 128, 0, stream>>>(FLt, FRt, FEAT, 128);
  k_build_feat<<<8192, 128, 0, stream>>>(FL1t, FR1t, FEAT1, 64);

  for (int l = 0; l < 6; ++l) {
    bool last = (l == 5);
    const bf16* iw  = SAIWb + (size_t)l * 4 * 384 * 128;
    const float* ib = SA_IB + (size_t)l * 4 * 384;
    const bf16* ow  = SAOWb + (size_t)l * 4 * 128 * 128;
    const float* ob = SA_OB + (size_t)l * 4 * 128;
    const bf16* ciw  = CAIWb + (size_t)l * 2 * 384 * 128;
    const float* cib = CA_IB + (size_t)l * 2 * 384;
    const bf16* cow  = CAOWb + (size_t)l * 2 * 128 * 128;
    const float* cob = CA_OB + (size_t)l * 2 * 128;
    const bf16* ciw1 = ciw + 384 * 128;
    const float* cib1 = cib + 384;
    const bf16* cow1 = cow + 128 * 128;
    const float* cob1 = cob + 128;
    const int IW = 384 * 128, OW = 128 * 128;

    // ======================= SELF =======================
    lnadd(LDesc{FEAT, Xb, SA_N1G + l * 128, SA_N1B + l * 128, 16384, 128, 128, 0});
    if (!last) lnadd(LDesc{FEAT1, XBb, SA_N2G + l * 128, SA_N2B + l * 128, 8192, 128, 128, 0});
    lnflush();
    G(Xb, iw + IW, ib + 384, QKV, nullptr, nullptr, 16384, 384, 128, 128, 128, 1, 128, 64, 0, 1, 1, 0);
    if (!last) G(XBb, iw + 3 * IW, ib + 3 * 384, QKV1, nullptr, nullptr, 8192, 384, 128, 128, 128, 1, 64, 64, 0, 1, 1, 0);
    G(PEYb, iw + IW, ib + 384, PP0b, nullptr, nullptr, 127, 256, 128, 128, 128, 0, 0, 0, 0, 1, 1, 0);
    if (!last) G(PEY1b, iw + 3 * IW, ib + 3 * 384, PP1b, nullptr, nullptr, 127, 256, 128, 128, 128, 0, 0, 0, 0, 1, 1, 0);
    gflush();
    AT(QKV, 384, QKV + 128, 384, QKV + 256, 384, PP0b, 64, 256, 1, Ob);
    if (!last) AT(QKV1, 384, QKV1 + 128, 384, QKV1 + 256, 384, PP1b, 64, 128, 1, Ob1);
    aflush();
    // FUSED y-out-proj + x-qkv
    G(Ob, W2b + (size_t)(l * 2) * 49152, B2f + (l * 2) * 384, QKV, nullptr, nullptr,
      16384, 384, 128, 128, 128, 1, 64, 128, 0, 1, 1, 0);
    if (!last) G(Ob1, W2b + (size_t)(l * 2 + 1) * 49152, B2f + (l * 2 + 1) * 384, QKV1,
                 nullptr, nullptr, 8192, 384, 128, 128, 128, 1, 64, 64, 0, 1, 1, 0);
    G(PEb, iw, ib, PP0b, nullptr, nullptr, 255, 256, 128, 128, 128, 0, 0, 0, 0, 1, 1, 0);
    if (!last) G(PE1b, iw + 2 * IW, ib + 2 * 384, PP1b, nullptr, nullptr, 127, 256, 128, 128, 128, 0, 0, 0, 0, 1, 1, 0);
    gflush();
    AT(QKV, 384, QKV + 128, 384, QKV + 256, 384, PP0b, 128, 128, 1, Ob);
    if (!last) AT(QKV1, 384, QKV1 + 128, 384, QKV1 + 256, 384, PP1b, 64, 128, 1, Ob1);
    aflush();
    G(Ob, ow, ob, nullptr, FEAT, FEAT, 16384, 128, 128, 128, 0, 0, 0, 0, 0, 1, 1, 0);
    if (!last) G(Ob1, ow + 2 * OW, ob + 2 * 128, nullptr, FEAT1, FEAT1, 8192, 128, 128, 128, 0, 0, 0, 0, 0, 1, 1, 0);
    gflush();

    // ======================= CROSS =======================
    lnadd(LDesc{FEAT, Xb, CA_N1G + l * 128, CA_N1B + l * 128, 8192, 64, 128, 0});
    lnadd(LDesc{FEAT, Xb + 1048576, CA_N1G + l * 128, CA_N1B + l * 128, 8192, 64, 128, 64});
    if (!last) {
      lnadd(LDesc{FEAT1, XBb, CA_N2G + l * 128, CA_N2B + l * 128, 4096, 64, 128, 0});
      lnadd(LDesc{FEAT1, XBb + 524288, CA_N2G + l * 128, CA_N2B + l * 128, 4096, 64, 128, 64});
    }
    lnflush();
    G(Xb, ciw, cib, QKV, nullptr, nullptr, 8192, 384, 128, 128, 128, 0, 0, 0, 0, 1, 1, 0);
    G(Xb + 1048576, ciw, cib, QR, nullptr, nullptr, 8192, 128, 128, 128, 128, 0, 0, 0, 0, 1, 1, 0);
    if (!last) {
      G(XBb, ciw1, cib1, FL4F, nullptr, nullptr, 4096, 384, 128, 128, 128, 0, 0, 0, 0, 1, 1, 0);
      G(XBb + 524288, ciw1, cib1, QR1, nullptr, nullptr, 4096, 128, 128, 128, 128, 0, 0, 0, 0, 1, 1, 0);
    }
    G(PEb, ciw, cib, PP0b, nullptr, nullptr, 255, 256, 128, 128, 128, 0, 0, 0, 0, 1, 1, 0);
    if (!last) G(PE1b, ciw1, cib1, PP1b, nullptr, nullptr, 127, 256, 128, 128, 128, 0, 0, 0, 0, 1, 1, 0);
    gflush();
    AT(QR, 128, QKV + 128, 384, QKV + 256, 384, PP0b, 128, 64, -1, Ob);
    if (!last) AT(QR1, 128, FL4F + 128, 384, FL4F + 256, 384, PP1b, 64, 64, -1, Ob1);
    aflush();
    G(Ob, cow, cob, nullptr, FEAT, FEAT, 8192, 128, 128, 128, 0, 0, 0, 0, 0, 64, 128, 64);
    if (!last) G(Ob1, cow1, cob1, nullptr, FN2, FEAT1, 4096, 128, 128, 128, 0, 0, 0, 0, 0, 64, 128, 64);
    gflush();
    lnadd(LDesc{FEAT, XR2, CA_N1G + l * 128, CA_N1B + l * 128, 8192, 64, 128, 64});
    if (!last) lnadd(LDesc{FN2, XR21, CA_N2G + l * 128, CA_N2B + l * 128, 4096, 64, 128, 64});
    lnflush();
    G(XR2, ciw + 128 * 128, cib + 128, KVq, nullptr, nullptr, 8192, 256, 128, 128, 0, 0, 0, 0, 0, 1, 1, 0);
    if (!last) G(XR21, ciw1 + 128 * 128, cib1 + 128, KVq1, nullptr, nullptr, 4096, 256, 128, 128, 0, 0, 0, 0, 0, 1, 1, 0);
    gflush();
    if (last) {
      // up_l raw scores (masked): in-block reduce -> d_out
      ADesc ad; ad.Q = QKV; ad.K = KVq; ad.V = KVq + 128; ad.PPb = PP0b;
      ad.O = (bf16*)d_out;
      ad.ldQ = 384; ad.ldK = 256; ad.ldV = 256;
      ad.Wlen = 128; ad.B = 64; ad.sflip = 1; ad.useMask = 1;
      k_attn_raw<<<64 * 8, 256, 0, stream>>>(ad);
      break;
    }
    AT(QKV, 384, KVq, 256, KVq + 128, 256, PP0b, 128, 64, 1, Ob);
    AT(FL4F, 384, KVq1, 256, KVq1 + 128, 256, PP1b, 64, 64, 1, Ob1);
    aflush();
    G(Ob, cow, cob, nullptr, FEAT, FEAT, 8192, 128, 128, 128, 0, 0, 0, 0, 0, 64, 128, 0);
    G(Ob1, cow1, cob1, nullptr, FN2, FEAT1, 4096, 128, 128, 128, 0, 0, 0, 0, 0, 64, 128, 0);
    gflush();
    G(nullptr, MW1b + (size_t)l * 128 * 256, MB1 + l * 128, Ob, nullptr, nullptr,
      16384, 128, 256, 256, 0, 3, 0, 0, 0, 1, 1, 0, FN2, FEAT);
    gflush();
    G(Ob, WFb + (size_t)l * 128 * 1152, MB2 + l * 128, nullptr, FEAT, nullptr,
      16384, 128, 1152, 128, 0, 2, 0, 0, 0, 1, 1, 0);
    gflush();
  }
}